// Round 4
// baseline (105.536 us; speedup 1.0000x reference)
//
#include <hip/hip_runtime.h>
#include <hip/hip_bf16.h>

// ComputeEmbeddings: out[b,s,d] = embed_weight[inputs[b,s], d] + PE[s,d]
//   B=32, S=5000, D=512, VOCAB=32000, fp32.
//
// R3 -> R4: invert gather into scatter. R3 post-mortem: nt stores neutral;
// dur matches ~660 MB @ 6.8 TB/s => random gathers re-fetch the full 328 MB
// logical read volume from HBM (reuses of a weight row are ~20us apart; L3
// doesn't hold them). Fix algorithmically: bucket positions by token
// (atomicAdd lists), then one block per vocab row reads the row ONCE
// (sequential 65.5 MB total) and scatters row+PE to all its uses.
// Traffic 660 -> ~396 MB.

#define EMB_B  32
#define EMB_S  5000
#define EMB_D  512
#define EMB_DV 128          // float4 per row
#define VOCAB  32000
#define CAP    32           // bucket capacity; P(Poisson(5)>32) ~ 1e-16/row,
                            // and build_lists has an inline overflow fallback.

typedef float f32x4 __attribute__((ext_vector_type(4)));

#define LOG2_10000 13.287712379549449f

// PE values for dims [dvec*4 .. dvec*4+3] at position s.
__device__ __forceinline__ f32x4 pe_quad(int s, int dvec) {
    const float i0 = (float)((dvec << 2) >> 1);
    const float f0 = exp2f(-(2.0f * i0 / (float)EMB_D) * LOG2_10000);
    const float f1 = exp2f(-(2.0f * (i0 + 1.0f) / (float)EMB_D) * LOG2_10000);
    const float a0 = (float)s * f0, a1 = (float)s * f1;
    f32x4 pe;
    pe.x = sinf(a0); pe.y = cosf(a0);
    pe.z = sinf(a1); pe.w = cosf(a1);
    return pe;
}

__global__ __launch_bounds__(256) void zero_counts_kernel(int* __restrict__ cnt) {
    const int i = blockIdx.x * blockDim.x + threadIdx.x;
    if (i < VOCAB) cnt[i] = 0;
}

__global__ __launch_bounds__(256) void build_lists_kernel(
    const int* __restrict__ inputs,     // [B*S]
    const float* __restrict__ weight,   // [VOCAB, D]
    int* __restrict__ cnt,              // [VOCAB]
    int* __restrict__ list,             // [VOCAB, CAP]
    float* __restrict__ out)            // [B*S, D] (overflow fallback only)
{
    const int i = blockIdx.x * blockDim.x + threadIdx.x;   // 0 .. B*S-1
    if (i >= EMB_B * EMB_S) return;
    const int v = inputs[i];
    const int slot = atomicAdd(&cnt[v], 1);
    if (slot < CAP) {
        list[v * CAP + slot] = i;
    } else {
        // Correctness net for pathological token distributions: do the
        // gather+PE+store for this position directly (expected never taken).
        const int s = i % EMB_S;
        const f32x4* __restrict__ w4 =
            reinterpret_cast<const f32x4*>(weight) + (size_t)v * EMB_DV;
        f32x4* __restrict__ o4 =
            reinterpret_cast<f32x4*>(out) + (size_t)i * EMB_DV;
        for (int dv = 0; dv < EMB_DV; ++dv)
            o4[dv] = w4[dv] + pe_quad(s, dv);
    }
}

// One 128-thread block per vocab row. Row is loaded once into registers;
// each use gets PE computed on the fly (4 transcendentals/thread/use) and
// a contiguous 2 KB store.
__global__ __launch_bounds__(128) void scatter_rows_kernel(
    const float* __restrict__ weight,
    const int* __restrict__ cnt,
    const int* __restrict__ list,
    float* __restrict__ out)
{
    const int v = blockIdx.x;           // vocab row
    const int lane = threadIdx.x;       // dvec 0..127
    int n = cnt[v];
    if (n > CAP) n = CAP;               // overflow handled in build_lists
    if (n == 0) return;

    const f32x4 w =
        reinterpret_cast<const f32x4*>(weight)[(size_t)v * EMB_DV + lane];

    // Per-thread PE frequency constants (fixed dvec across uses).
    const float i0 = (float)((lane << 2) >> 1);
    const float f0 = exp2f(-(2.0f * i0 / (float)EMB_D) * LOG2_10000);
    const float f1 = exp2f(-(2.0f * (i0 + 1.0f) / (float)EMB_D) * LOG2_10000);

    f32x4* __restrict__ o4 = reinterpret_cast<f32x4*>(out);
    for (int u = 0; u < n; ++u) {
        const int pos = list[v * CAP + u];   // b*S + s (wave-uniform)
        const int s = pos % EMB_S;
        const float a0 = (float)s * f0, a1 = (float)s * f1;
        f32x4 r;
        r.x = w.x + sinf(a0);
        r.y = w.y + cosf(a0);
        r.z = w.z + sinf(a1);
        r.w = w.w + cosf(a1);
        o4[(size_t)pos * EMB_DV + lane] = r;
    }
}

// Fallback (R3 forward kernel) if ws_size is too small for the buckets.
__global__ __launch_bounds__(256) void forward_kernel(
    const int* __restrict__ inputs,
    const float* __restrict__ weight,
    float* __restrict__ out)
{
    const int tid = blockIdx.x * blockDim.x + threadIdx.x;
    const int dvec = tid & (EMB_DV - 1);
    const int s    = tid >> 7;
    if (s >= EMB_S) return;

    int tokens[EMB_B];
    #pragma unroll
    for (int b = 0; b < EMB_B; ++b) tokens[b] = inputs[b * EMB_S + s];

    const f32x4 pe = pe_quad(s, dvec);
    const f32x4* __restrict__ w4 = reinterpret_cast<const f32x4*>(weight);
    f32x4* __restrict__ o4 = reinterpret_cast<f32x4*>(out);
    const int row_off = s * EMB_DV + dvec;

    #pragma unroll 8
    for (int b = 0; b < EMB_B; ++b) {
        const f32x4 e = w4[(size_t)tokens[b] * EMB_DV + dvec];
        o4[(size_t)b * (EMB_S * EMB_DV) + row_off] = e + pe;
    }
}

extern "C" void kernel_launch(void* const* d_in, const int* in_sizes, int n_in,
                              void* d_out, int out_size, void* d_ws, size_t ws_size,
                              hipStream_t stream) {
    const int*   inputs = (const int*)d_in[0];     // [32, 5000] int32
    const float* weight = (const float*)d_in[1];   // [32000, 512] fp32
    float*       out    = (float*)d_out;           // [32, 5000, 512] fp32

    const size_t cnt_bytes  = (size_t)VOCAB * sizeof(int);          // 128 KB
    const size_t list_bytes = (size_t)VOCAB * CAP * sizeof(int);    // 4 MB
    if (ws_size >= cnt_bytes + list_bytes) {
        int* cnt  = (int*)d_ws;
        int* list = (int*)((char*)d_ws + cnt_bytes);

        zero_counts_kernel<<<(VOCAB + 255) / 256, 256, 0, stream>>>(cnt);

        const int npos = EMB_B * EMB_S;  // 160,000
        build_lists_kernel<<<(npos + 255) / 256, 256, 0, stream>>>(
            inputs, weight, cnt, list, out);

        scatter_rows_kernel<<<VOCAB, 128, 0, stream>>>(weight, cnt, list, out);
    } else {
        const int total_threads = EMB_S * EMB_DV;
        forward_kernel<<<(total_threads + 255) / 256, 256, 0, stream>>>(
            inputs, weight, out);
    }
}